// Round 4
// baseline (9514.609 us; speedup 1.0000x reference)
//
#include <hip/hip_runtime.h>
#include <hip/hip_bf16.h>

using bf16 = __hip_bfloat16;

static __device__ __forceinline__ float b2f(bf16 v){ return __bfloat162float(v); }
static __device__ __forceinline__ float toF(float v){ return v; }
static __device__ __forceinline__ float toF(bf16 v){ return __bfloat162float(v); }
// dtype-adaptive input load: f32 flag selects interpretation; i is ELEMENT index
static __device__ __forceinline__ float ld(const void* p, size_t i, int f32){
  return f32 ? ((const float*)p)[i] : __bfloat162float(((const bf16*)p)[i]);
}

constexpr int Bn = 4, Np = 1024, Gn = 128, Kn = 32;
constexpr int DM = 384, DEPTH = 12, CLSn = 40;
constexpr int DI = 768, DSt = 16, DTR = 24;
constexpr int Ln = 384;
constexpr float EPSf = 1e-5f;
constexpr float BNS = 0.99999500003749968752f; // 1/sqrt(1+1e-5)
constexpr float LOG2E = 1.4426950408889634f;

// ---------------------------------------------------------------- dtype detector
__global__ __launch_bounds__(64) void detect_kernel(const void* __restrict__ pts,
                                                    int* __restrict__ flag){
  int t = threadIdx.x;
  const bf16* p = (const bf16*)pts;
  float m = 0.f;
  for (int i = t; i < 256; i += 64){
    float v = fabsf(b2f(p[i]));
    if (!(v <= 1e6f)) m = 1e30f;   // catches NaN and big
    else m = fmaxf(m, v);
  }
  #pragma unroll
  for (int o = 32; o > 0; o >>= 1) m = fmaxf(m, __shfl_down(m, o));
  if (t == 0) flag[0] = (m > 1e6f) ? 1 : 0;   // 1 = fp32 data
}

// ---------------------------------------------------------------- FPS
__global__ __launch_bounds__(256) void fps_kernel(const void* __restrict__ pts,
                                                  float* __restrict__ center,
                                                  const int* __restrict__ dflag){
  const int f32 = *dflag;
  int b = blockIdx.x;
  __shared__ float xs[1024], ys[1024], zs[1024], dmin[1024];
  __shared__ float rv[4]; __shared__ int ri[4];
  __shared__ int s_last;
  int t = threadIdx.x;
  size_t base = (size_t)b * Np * 3;
  for (int n = t; n < Np; n += 256){
    xs[n] = ld(pts, base + n*3+0, f32);
    ys[n] = ld(pts, base + n*3+1, f32);
    zs[n] = ld(pts, base + n*3+2, f32);
    dmin[n] = 1e10f;
  }
  __syncthreads();
  if (t == 0){
    s_last = 0;
    center[(size_t)(b*Gn)*3+0] = xs[0];
    center[(size_t)(b*Gn)*3+1] = ys[0];
    center[(size_t)(b*Gn)*3+2] = zs[0];
  }
  __syncthreads();
  int last = 0;
  for (int it = 1; it < Gn; ++it){
    float px = xs[last], py = ys[last], pz = zs[last];
    float v = -1.f; int idx = 0;
    for (int n = t; n < Np; n += 256){
      float dx = __fsub_rn(xs[n], px);
      float dy = __fsub_rn(ys[n], py);
      float dz = __fsub_rn(zs[n], pz);
      float d  = __fadd_rn(__fadd_rn(__fmul_rn(dx,dx), __fmul_rn(dy,dy)), __fmul_rn(dz,dz));
      float dm = fminf(dmin[n], d); dmin[n] = dm;
      if (dm > v || (dm == v && n < idx)){ v = dm; idx = n; }
    }
    #pragma unroll
    for (int o = 32; o > 0; o >>= 1){
      float v2 = __shfl_down(v, o); int i2 = __shfl_down(idx, o);
      if (v2 > v || (v2 == v && i2 < idx)){ v = v2; idx = i2; }
    }
    if ((t & 63) == 0){ rv[t>>6] = v; ri[t>>6] = idx; }
    __syncthreads();
    if (t == 0){
      float bv = rv[0]; int bi = ri[0];
      for (int w = 1; w < 4; ++w){
        if (rv[w] > bv || (rv[w] == bv && ri[w] < bi)){ bv = rv[w]; bi = ri[w]; }
      }
      bi = min(max(bi, 0), Np-1);
      s_last = bi;
      center[(size_t)(b*Gn+it)*3+0] = xs[bi];
      center[(size_t)(b*Gn+it)*3+1] = ys[bi];
      center[(size_t)(b*Gn+it)*3+2] = zs[bi];
    }
    __syncthreads();
    last = s_last;
  }
}

// ---------------------------------------------------------------- KNN
__global__ __launch_bounds__(256) void knn_kernel(const void* __restrict__ pts,
                                                  const float* __restrict__ center,
                                                  float* __restrict__ nb,
                                                  const int* __restrict__ dflag){
  const int f32 = *dflag;
  int gid = blockIdx.x; int b = gid >> 7;
  __shared__ float d2[1024];
  __shared__ float rv[4]; __shared__ int ri[4];
  int t = threadIdx.x;
  float cx = center[(size_t)gid*3+0], cy = center[(size_t)gid*3+1], cz = center[(size_t)gid*3+2];
  size_t base = (size_t)b * Np * 3;
  for (int n = t; n < Np; n += 256){
    float dx = __fsub_rn(cx, ld(pts, base + n*3+0, f32));
    float dy = __fsub_rn(cy, ld(pts, base + n*3+1, f32));
    float dz = __fsub_rn(cz, ld(pts, base + n*3+2, f32));
    d2[n] = __fadd_rn(__fadd_rn(__fmul_rn(dx,dx), __fmul_rn(dy,dy)), __fmul_rn(dz,dz));
  }
  __syncthreads();
  for (int kk = 0; kk < Kn; ++kk){
    float v = 3e38f; int idx = 0;
    for (int n = t; n < Np; n += 256){
      float d = d2[n];
      if (d < v || (d == v && n < idx)){ v = d; idx = n; }
    }
    #pragma unroll
    for (int o = 32; o > 0; o >>= 1){
      float v2 = __shfl_down(v, o); int i2 = __shfl_down(idx, o);
      if (v2 < v || (v2 == v && i2 < idx)){ v = v2; idx = i2; }
    }
    if ((t & 63) == 0){ rv[t>>6] = v; ri[t>>6] = idx; }
    __syncthreads();
    if (t == 0){
      float bv = rv[0]; int bi = ri[0];
      for (int w = 1; w < 4; ++w){
        if (rv[w] < bv || (rv[w] == bv && ri[w] < bi)){ bv = rv[w]; bi = ri[w]; }
      }
      bi = min(max(bi, 0), Np-1);
      nb[((size_t)gid*Kn+kk)*3+0] = __fsub_rn(ld(pts, base + bi*3+0, f32), cx);
      nb[((size_t)gid*Kn+kk)*3+1] = __fsub_rn(ld(pts, base + bi*3+1, f32), cy);
      nb[((size_t)gid*Kn+kk)*3+2] = __fsub_rn(ld(pts, base + bi*3+2, f32), cz);
      d2[bi] = 3e38f;
    }
    __syncthreads();
  }
}

// ---------------------------------------------------------------- GEMM
// C[M,N] = act(A[M,K](lda) @ W[N,K]^T + bias). W/bias/g/bb are input tensors
// addressed at element offset (wOff etc.) with runtime dtype.
template<typename AT, int ACT>
__global__ __launch_bounds__(256) void gemm_bt(const AT* __restrict__ A, int lda,
                                               const void* __restrict__ W, size_t wOff,
                                               const void* __restrict__ bias, size_t bOff,
                                               const void* __restrict__ g,
                                               const void* __restrict__ bb,
                                               float* __restrict__ C, int ldc,
                                               int M, int N, int K,
                                               const int* __restrict__ dflag){
  const int f32 = *dflag;
  __shared__ __align__(16) float As[16][68];
  __shared__ __align__(16) float Ws[16][68];
  int bm = blockIdx.x * 64, bn = blockIdx.y * 64;
  int t = threadIdx.x;
  int tx = t & 15, ty = t >> 4;
  int lm = t >> 2;
  int lk = (t & 3) * 4;
  float acc[4][4] = {};
  for (int k0 = 0; k0 < K; k0 += 16){
    {
      int m = bm + lm;
      #pragma unroll
      for (int i = 0; i < 4; ++i){
        int k = k0 + lk + i;
        As[lk+i][lm] = (k < K) ? toF(A[(size_t)m*lda + k]) : 0.f;
      }
    }
    {
      int n = bn + lm;
      #pragma unroll
      for (int i = 0; i < 4; ++i){
        int k = k0 + lk + i;
        float wv = 0.f;
        if (n < N && k < K) wv = ld(W, wOff + (size_t)n*K + k, f32);
        Ws[lk+i][lm] = wv;
      }
    }
    __syncthreads();
    #pragma unroll
    for (int kk = 0; kk < 16; ++kk){
      float4 av = *(const float4*)(&As[kk][ty*4]);
      float4 wv = *(const float4*)(&Ws[kk][tx*4]);
      float a4[4] = {av.x, av.y, av.z, av.w};
      float w4[4] = {wv.x, wv.y, wv.z, wv.w};
      #pragma unroll
      for (int i = 0; i < 4; ++i)
        #pragma unroll
        for (int j = 0; j < 4; ++j)
          acc[i][j] += a4[i] * w4[j];
    }
    __syncthreads();
  }
  #pragma unroll
  for (int i = 0; i < 4; ++i){
    int m = bm + ty*4 + i;
    #pragma unroll
    for (int j = 0; j < 4; ++j){
      int n = bn + tx*4 + j;
      if (n < N){
        float v = acc[i][j];
        if (bias) v += ld(bias, bOff + n, f32);
        if (ACT == 1){ v = v * (ld(g, n, f32) * BNS) + ld(bb, n, f32); v = fmaxf(v, 0.f); }
        C[(size_t)m*ldc + n] = v;
      }
    }
  }
}

// -------------------------------------------------- encoder max-pools
__global__ __launch_bounds__(256) void maxk_fg(float* __restrict__ f3in){
  int gg = blockIdx.x; int c = threadIdx.x;
  float m = -3e38f;
  for (int k = 0; k < Kn; ++k) m = fmaxf(m, f3in[((size_t)gg*Kn + k)*512 + 256 + c]);
  for (int k = 0; k < Kn; ++k) f3in[((size_t)gg*Kn + k)*512 + c] = m;
}

__global__ __launch_bounds__(384) void maxk_tok(const float* __restrict__ f4, float* __restrict__ tok){
  int gg = blockIdx.x; int c = threadIdx.x;
  float m = -3e38f;
  for (int k = 0; k < Kn; ++k) m = fmaxf(m, f4[((size_t)gg*Kn + k)*DM + c]);
  tok[(size_t)gg*DM + c] = m;
}

// -------------------------------------------------- pos embedding (adds into tok)
__global__ __launch_bounds__(128) void pos_kernel(const float* __restrict__ center,
                                                  const void* __restrict__ w1, const void* __restrict__ b1,
                                                  const void* __restrict__ w2, const void* __restrict__ b2,
                                                  float* __restrict__ tok,
                                                  const int* __restrict__ dflag){
  const int f32 = *dflag;
  int gid = blockIdx.x;
  __shared__ float h1[128]; __shared__ float c3[3];
  int t = threadIdx.x;
  if (t < 3) c3[t] = center[(size_t)gid*3 + t];
  __syncthreads();
  float a = ld(w1,t*3+0,f32)*c3[0] + ld(w1,t*3+1,f32)*c3[1] + ld(w1,t*3+2,f32)*c3[2] + ld(b1,t,f32);
  h1[t] = 0.5f * a * (1.f + erff(a * 0.70710678118654752440f));
  __syncthreads();
  for (int c = t; c < DM; c += 128){
    float s = ld(b2, c, f32);
    for (int j = 0; j < 128; ++j) s += ld(w2, (size_t)c*128 + j, f32) * h1[j];
    tok[(size_t)gid*DM + c] += s;
  }
}

// -------------------------------------------------- stable argsort (rank count)
__global__ __launch_bounds__(128) void sort_kernel(const float* __restrict__ center,
                                                   int* __restrict__ order){
  int bax = blockIdx.x; int b = bax / 3, ax = bax % 3;
  __shared__ float key[128];
  int t = threadIdx.x;
  key[t] = center[(size_t)(b*Gn + t)*3 + ax];
  __syncthreads();
  float kt = key[t]; int r = 0;
  for (int j = 0; j < Gn; ++j){
    float kj = key[j];
    r += (kj < kt || (kj == kt && j < t)) ? 1 : 0;
  }
  r = min(max(r, 0), Gn-1);
  order[b*Ln + ax*Gn + r] = t;
}

// -------------------------------------------------- token gather + res init
__global__ __launch_bounds__(256) void build_h(const float* __restrict__ tok,
                        const int* __restrict__ order,
                        float* __restrict__ h, float* __restrict__ res){
  int i = blockIdx.x * blockDim.x + threadIdx.x;
  if (i >= Bn*Ln*DM) return;
  int c = i % DM; int l = (i / DM) % Ln; int b = i / (DM*Ln);
  int src = order[b*Ln + l];
  src = min(max(src, 0), Gn-1);
  h[i] = tok[((size_t)(b*Gn + src))*DM + c];
  res[i] = 0.f;
}

// -------------------------------------------------- res += h; x = LN(res)*w+b (bf16 out)
__global__ __launch_bounds__(256) void ln_res_kernel(const float* __restrict__ h,
                                                     float* __restrict__ res,
                                                     bf16* __restrict__ x,
                                                     const void* __restrict__ w, size_t wOff,
                                                     const void* __restrict__ bias,
                                                     const int* __restrict__ dflag){
  const int f32 = *dflag;
  int wv = threadIdx.x >> 6, ln = threadIdx.x & 63;
  int tokid = blockIdx.x*4 + wv;
  const float* hr = h + (size_t)tokid*DM;
  float* rr = res + (size_t)tokid*DM;
  bf16* xr = x + (size_t)tokid*DM;
  float v[6]; float s = 0.f;
  #pragma unroll
  for (int i = 0; i < 6; ++i){ int c = ln + 64*i; float t = hr[c] + rr[c]; rr[c] = t; v[i] = t; s += t; }
  #pragma unroll
  for (int o = 32; o > 0; o >>= 1) s += __shfl_xor(s, o);
  float mu = s * (1.f/DM);
  float q = 0.f;
  #pragma unroll
  for (int i = 0; i < 6; ++i){ float d = v[i] - mu; q += d*d; }
  #pragma unroll
  for (int o = 32; o > 0; o >>= 1) q += __shfl_xor(q, o);
  float rstd = rsqrtf(q * (1.f/DM) + EPSf);
  #pragma unroll
  for (int i = 0; i < 6; ++i){ int c = ln + 64*i;
    xr[c] = __float2bfloat16((v[i]-mu)*rstd*ld(w, wOff+c, f32) + ld(bias, wOff+c, f32)); }
}

// -------------------------------------------------- causal depthwise conv + silu
__global__ __launch_bounds__(256) void conv_kernel(float* __restrict__ xz,
                                                   const void* __restrict__ cw, size_t cwOff,
                                                   const void* __restrict__ cb, size_t cbOff,
                                                   const int* __restrict__ dflag){
  const int f32 = *dflag;
  int id = blockIdx.x * 256 + threadIdx.x;
  int b = id / DI, d = id % DI;
  float w0 = ld(cw, cwOff + d*4+0, f32), w1 = ld(cw, cwOff + d*4+1, f32);
  float w2 = ld(cw, cwOff + d*4+2, f32), w3 = ld(cw, cwOff + d*4+3, f32);
  float bias = ld(cb, cbOff + d, f32);
  float* p = xz + (size_t)b*Ln*1536 + d;
  float u0 = 0.f, u1 = 0.f, u2 = 0.f;
  for (int l = 0; l < Ln; ++l){
    float u3 = p[(size_t)l*1536];
    float v = u0*w0 + u1*w1 + u2*w2 + u3*w3 + bias;
    v = v / (1.f + expf(-v));
    p[(size_t)l*1536] = v;
    u0 = u1; u1 = u2; u2 = u3;
  }
}

// -------------------------------------------------- selective scan (dt_proj fused)
__global__ __launch_bounds__(256) void scan_kernel(float* __restrict__ xz,
                                                   const float* __restrict__ xdb,
                                                   const void* __restrict__ dpw, size_t dpwOff,
                                                   const void* __restrict__ dpb, size_t dpbOff,
                                                   const void* __restrict__ A_log, size_t AlOff,
                                                   const void* __restrict__ Dp, size_t DpOff,
                                                   const int* __restrict__ dflag){
  const int f32 = *dflag;
  __shared__ float sRow[128*56];
  int blk = blockIdx.x; int b = blk / 3; int dch = blk % 3;
  int t = threadIdx.x; int d = dch*256 + t;
  float w[DTR], a2[DSt], h[DSt];
  #pragma unroll
  for (int j = 0; j < DTR; ++j) w[j] = ld(dpw, dpwOff + (size_t)d*DTR + j, f32);
  #pragma unroll
  for (int s = 0; s < DSt; ++s){ a2[s] = -expf(ld(A_log, AlOff + (size_t)d*DSt + s, f32)) * LOG2E; h[s] = 0.f; }
  float dbias = ld(dpb, dpbOff + d, f32);
  float Dd = ld(Dp, DpOff + d, f32);
  float* xzu = xz + (size_t)b*Ln*1536 + d;
  for (int c = 0; c < 3; ++c){
    const float* src = xdb + ((size_t)b*Ln + c*128)*56;
    __syncthreads();
    for (int i = t; i < 128*56; i += 256) sRow[i] = src[i];
    __syncthreads();
    for (int ll = 0; ll < 128; ++ll){
      int l = c*128 + ll;
      const float* row = &sRow[ll*56];
      float dtr = dbias;
      #pragma unroll
      for (int j = 0; j < DTR; ++j) dtr += w[j] * row[j];
      float dtv = fmaxf(dtr, 0.f) + log1pf(expf(-fabsf(dtr)));
      float uv = xzu[(size_t)l*1536];
      float du = dtv * uv;
      float yv = 0.f;
      #pragma unroll
      for (int s = 0; s < DSt; ++s){
        h[s] = exp2f(dtv * a2[s]) * h[s] + du * row[24 + s];
        yv += h[s] * row[40 + s];
      }
      float zv = xzu[(size_t)l*1536 + DI];
      float sig = 1.f / (1.f + expf(-zv));
      xzu[(size_t)l*1536] = (yv + uv*Dd) * (zv * sig);
    }
  }
}

// -------------------------------------------------- final two LayerNorms
__global__ __launch_bounds__(256) void final_ln_kernel(const float* __restrict__ h,
                                                       const float* __restrict__ res,
                                                       const void* w1, const void* b1,
                                                       const void* w2, const void* b2,
                                                       float* __restrict__ x,
                                                       const int* __restrict__ dflag){
  const int f32 = *dflag;
  int wv = threadIdx.x >> 6, ln = threadIdx.x & 63;
  int tokid = blockIdx.x*4 + wv;
  const float* hr = h + (size_t)tokid*DM;
  const float* rr = res + (size_t)tokid*DM;
  float* xr = x + (size_t)tokid*DM;
  float v[6]; float s = 0.f;
  #pragma unroll
  for (int i = 0; i < 6; ++i){ int c = ln + 64*i; v[i] = hr[c] + rr[c]; s += v[i]; }
  #pragma unroll
  for (int o = 32; o > 0; o >>= 1) s += __shfl_xor(s, o);
  float mu = s * (1.f/DM); float q = 0.f;
  #pragma unroll
  for (int i = 0; i < 6; ++i){ float dd = v[i]-mu; q += dd*dd; }
  #pragma unroll
  for (int o = 32; o > 0; o >>= 1) q += __shfl_xor(q, o);
  float rstd = rsqrtf(q * (1.f/DM) + EPSf);
  float u[6]; float s2 = 0.f;
  #pragma unroll
  for (int i = 0; i < 6; ++i){ int c = ln + 64*i; u[i] = (v[i]-mu)*rstd*ld(w1,c,f32) + ld(b1,c,f32); s2 += u[i]; }
  #pragma unroll
  for (int o = 32; o > 0; o >>= 1) s2 += __shfl_xor(s2, o);
  float mu2 = s2 * (1.f/DM); float q2 = 0.f;
  #pragma unroll
  for (int i = 0; i < 6; ++i){ float dd = u[i]-mu2; q2 += dd*dd; }
  #pragma unroll
  for (int o = 32; o > 0; o >>= 1) q2 += __shfl_xor(q2, o);
  float rstd2 = rsqrtf(q2 * (1.f/DM) + EPSf);
  #pragma unroll
  for (int i = 0; i < 6; ++i){ int c = ln + 64*i; xr[c] = (u[i]-mu2)*rstd2*ld(w2,c,f32) + ld(b2,c,f32); }
}

// -------------------------------------------------- mean over L + MLP head
__global__ __launch_bounds__(384) void head_kernel(const float* __restrict__ x,
    const void* w1, const void* b1, const void* g1, const void* bb1,
    const void* w2, const void* b2, const void* g2, const void* bb2,
    const void* w3, const void* b3, void* __restrict__ out,
    const int* __restrict__ dflag){
  const int f32 = *dflag;
  int b = blockIdx.x; int t = threadIdx.x;
  __shared__ float feat[DM]; __shared__ float h1[256]; __shared__ float h2[256];
  float s = 0.f;
  for (int l = 0; l < Ln; ++l) s += x[((size_t)(b*Ln + l))*DM + t];
  feat[t] = s * (1.f/Ln);
  __syncthreads();
  if (t < 256){
    float a = ld(b1, t, f32);
    for (int j = 0; j < DM; ++j) a += ld(w1, (size_t)t*DM + j, f32) * feat[j];
    a = a * (ld(g1,t,f32) * BNS) + ld(bb1,t,f32);
    h1[t] = fmaxf(a, 0.f);
  }
  __syncthreads();
  if (t < 256){
    float a = ld(b2, t, f32);
    for (int j = 0; j < 256; ++j) a += ld(w2, (size_t)t*256 + j, f32) * h1[j];
    a = a * (ld(g2,t,f32) * BNS) + ld(bb2,t,f32);
    h2[t] = fmaxf(a, 0.f);
  }
  __syncthreads();
  if (t < CLSn){
    float a = ld(b3, t, f32);
    for (int j = 0; j < 256; ++j) a += ld(w3, (size_t)t*256 + j, f32) * h2[j];
    if (f32) ((float*)out)[b*CLSn + t] = a;
    else     ((bf16*)out)[b*CLSn + t] = __float2bfloat16(a);
  }
}

extern "C" void kernel_launch(void* const* d_in, const int* in_sizes, int n_in,
                              void* d_out, int out_size, void* d_ws, size_t ws_size,
                              hipStream_t stream) {
  if (n_in < 42) return;
  if (out_size < Bn*CLSn) return;
  constexpr size_t WS_FLOATS = 3919936; // hb + res + U + flag
  if (ws_size < WS_FLOATS * sizeof(float)) return;

  const void* pts       = d_in[0];
  const void* enc_w1    = d_in[1];  const void* enc_b1    = d_in[2];
  const void* enc_bn1_g = d_in[3];  const void* enc_bn1_b = d_in[4];
  const void* enc_w2    = d_in[5];  const void* enc_b2    = d_in[6];
  const void* enc_w3    = d_in[7];  const void* enc_b3    = d_in[8];
  const void* enc_bn2_g = d_in[9];  const void* enc_bn2_b = d_in[10];
  const void* enc_w4    = d_in[11]; const void* enc_b4    = d_in[12];
  const void* pos_w1    = d_in[13]; const void* pos_b1    = d_in[14];
  const void* pos_w2    = d_in[15]; const void* pos_b2    = d_in[16];
  const void* ln_w      = d_in[17]; const void* ln_b      = d_in[18];
  const void* in_proj_w = d_in[19];
  const void* conv_w    = d_in[20]; const void* conv_b    = d_in[21];
  const void* x_proj_w  = d_in[22];
  const void* dt_proj_w = d_in[23]; const void* dt_proj_b = d_in[24];
  const void* A_log     = d_in[25]; const void* D_param   = d_in[26];
  const void* out_proj_w= d_in[27];
  const void* normf_w   = d_in[28]; const void* normf_b   = d_in[29];
  const void* norm_w    = d_in[30]; const void* norm_b    = d_in[31];
  const void* head_w1   = d_in[32]; const void* head_b1   = d_in[33];
  const void* head_bn1_g= d_in[34]; const void* head_bn1_b= d_in[35];
  const void* head_w2   = d_in[36]; const void* head_b2   = d_in[37];
  const void* head_bn2_g= d_in[38]; const void* head_bn2_b= d_in[39];
  const void* head_w3   = d_in[40]; const void* head_b3   = d_in[41];

  float* ws = (float*)d_ws;
  float* hb   = ws;                   // 589,824 floats
  float* resb = ws + 589824;          // 589,824
  float* U    = ws + 1179648;         // 2,740,224
  int* dflag  = (int*)(ws + 3919872); // flag slot
  // setup/encoder view of U
  float* center = U;
  float* nb     = U + 1536;
  float* tok    = U + 50688;
  int*   order  = (int*)(U + 247296);
  float* eb0    = U + 262144;
  float* eb1    = U + 1310720;
  // mamba view of U
  float* xz  = U;
  float* xdb = U + 2359296;
  bf16*  xb  = (bf16*)(U + 2445312);
  float* xf  = U;

  detect_kernel<<<1, 64, 0, stream>>>(pts, dflag);

  fps_kernel<<<Bn, 256, 0, stream>>>(pts, center, dflag);
  knn_kernel<<<Bn*Gn, 256, 0, stream>>>(pts, center, nb, dflag);

  for (int ch = 0; ch < 8; ++ch){
    const float* nb_c = nb + (size_t)ch*2048*3;
    float* tok_c = tok + (size_t)ch*64*DM;
    gemm_bt<float,1><<<dim3(32,2), 256, 0, stream>>>(nb_c, 3, enc_w1, 0, enc_b1, 0,
        enc_bn1_g, enc_bn1_b, eb1, 128, 2048, 128, 3, dflag);
    gemm_bt<float,0><<<dim3(32,4), 256, 0, stream>>>(eb1, 128, enc_w2, 0, enc_b2, 0,
        nullptr, nullptr, eb0 + 256, 512, 2048, 256, 128, dflag);
    maxk_fg<<<64, 256, 0, stream>>>(eb0);
    gemm_bt<float,1><<<dim3(32,8), 256, 0, stream>>>(eb0, 512, enc_w3, 0, enc_b3, 0,
        enc_bn2_g, enc_bn2_b, eb1, 512, 2048, 512, 512, dflag);
    gemm_bt<float,0><<<dim3(32,6), 256, 0, stream>>>(eb1, 512, enc_w4, 0, enc_b4, 0,
        nullptr, nullptr, eb0, 384, 2048, 384, 512, dflag);
    maxk_tok<<<64, 384, 0, stream>>>(eb0, tok_c);
  }

  pos_kernel<<<Bn*Gn, 128, 0, stream>>>(center, pos_w1, pos_b1, pos_w2, pos_b2, tok, dflag);
  sort_kernel<<<Bn*3, 128, 0, stream>>>(center, order);
  build_h<<<(Bn*Ln*DM + 255)/256, 256, 0, stream>>>(tok, order, hb, resb);

  for (int l = 0; l < DEPTH; ++l){
    size_t o_ln  = (size_t)l*DM;
    size_t o_ip  = (size_t)l*1536*DM;
    size_t o_cw  = (size_t)l*DI*4;
    size_t o_cb  = (size_t)l*DI;
    size_t o_xp  = (size_t)l*56*DI;
    size_t o_dpw = (size_t)l*DI*DTR;
    size_t o_dpb = (size_t)l*DI;
    size_t o_Al  = (size_t)l*DI*DSt;
    size_t o_Dp  = (size_t)l*DI;
    size_t o_op  = (size_t)l*DM*DI;

    ln_res_kernel<<<Bn*Ln/4, 256, 0, stream>>>(hb, resb, xb, ln_w, o_ln, ln_b, dflag);
    gemm_bt<bf16,0><<<dim3(24,24), 256, 0, stream>>>(xb, DM, in_proj_w, o_ip,
        nullptr, 0, nullptr, nullptr, xz, 1536, Bn*Ln, 1536, DM, dflag);
    conv_kernel<<<Bn*DI/256, 256, 0, stream>>>(xz, conv_w, o_cw, conv_b, o_cb, dflag);
    gemm_bt<float,0><<<dim3(24,1), 256, 0, stream>>>(xz, 1536, x_proj_w, o_xp,
        nullptr, 0, nullptr, nullptr, xdb, 56, Bn*Ln, 56, DI, dflag);
    scan_kernel<<<Bn*3, 256, 0, stream>>>(xz, xdb, dt_proj_w, o_dpw, dt_proj_b, o_dpb,
        A_log, o_Al, D_param, o_Dp, dflag);
    gemm_bt<float,0><<<dim3(24,6), 256, 0, stream>>>(xz, 1536, out_proj_w, o_op,
        nullptr, 0, nullptr, nullptr, hb, DM, Bn*Ln, DM, DI, dflag);
  }

  final_ln_kernel<<<Bn*Ln/4, 256, 0, stream>>>(hb, resb, normf_w, normf_b, norm_w, norm_b, xf, dflag);
  head_kernel<<<Bn, 384, 0, stream>>>(xf, head_w1, head_b1, head_bn1_g, head_bn1_b,
                                      head_w2, head_b2, head_bn2_g, head_bn2_b,
                                      head_w3, head_b3, d_out, dflag);
}

// Round 5
// 6300.262 us; speedup vs baseline: 1.5102x; 1.5102x over previous
//
#include <hip/hip_runtime.h>
#include <hip/hip_bf16.h>

using bf16 = __hip_bfloat16;

static __device__ __forceinline__ float b2f(bf16 v){ return __bfloat162float(v); }
static __device__ __forceinline__ float toF(float v){ return v; }
static __device__ __forceinline__ float toF(bf16 v){ return __bfloat162float(v); }
// dtype-adaptive input load: f32 flag selects interpretation; i is ELEMENT index
static __device__ __forceinline__ float ld(const void* p, size_t i, int f32){
  return f32 ? ((const float*)p)[i] : __bfloat162float(((const bf16*)p)[i]);
}

constexpr int Bn = 4, Np = 1024, Gn = 128, Kn = 32;
constexpr int DM = 384, DEPTH = 12, CLSn = 40;
constexpr int DI = 768, DSt = 16, DTR = 24;
constexpr int Ln = 384;
constexpr int NCH = 12, CHS = 32;      // scan: 12 chunks x 32 steps
constexpr float EPSf = 1e-5f;
constexpr float BNS = 0.99999500003749968752f; // 1/sqrt(1+1e-5)
constexpr float LOG2E = 1.4426950408889634f;

// ---------------------------------------------------------------- dtype detector
__global__ __launch_bounds__(64) void detect_kernel(const void* __restrict__ pts,
                                                    int* __restrict__ flag){
  int t = threadIdx.x;
  const bf16* p = (const bf16*)pts;
  float m = 0.f;
  for (int i = t; i < 256; i += 64){
    float v = fabsf(b2f(p[i]));
    if (!(v <= 1e6f)) m = 1e30f;
    else m = fmaxf(m, v);
  }
  #pragma unroll
  for (int o = 32; o > 0; o >>= 1) m = fmaxf(m, __shfl_down(m, o));
  if (t == 0) flag[0] = (m > 1e6f) ? 1 : 0;   // 1 = fp32 data
}

// ---------------------------------------------------------------- FPS
__global__ __launch_bounds__(256) void fps_kernel(const void* __restrict__ pts,
                                                  float* __restrict__ center,
                                                  const int* __restrict__ dflag){
  const int f32 = *dflag;
  int b = blockIdx.x;
  __shared__ float xs[1024], ys[1024], zs[1024], dmin[1024];
  __shared__ float rv[4]; __shared__ int ri[4];
  __shared__ int s_last;
  int t = threadIdx.x;
  size_t base = (size_t)b * Np * 3;
  for (int n = t; n < Np; n += 256){
    xs[n] = ld(pts, base + n*3+0, f32);
    ys[n] = ld(pts, base + n*3+1, f32);
    zs[n] = ld(pts, base + n*3+2, f32);
    dmin[n] = 1e10f;
  }
  __syncthreads();
  if (t == 0){
    s_last = 0;
    center[(size_t)(b*Gn)*3+0] = xs[0];
    center[(size_t)(b*Gn)*3+1] = ys[0];
    center[(size_t)(b*Gn)*3+2] = zs[0];
  }
  __syncthreads();
  int last = 0;
  for (int it = 1; it < Gn; ++it){
    float px = xs[last], py = ys[last], pz = zs[last];
    float v = -1.f; int idx = 0;
    for (int n = t; n < Np; n += 256){
      float dx = __fsub_rn(xs[n], px);
      float dy = __fsub_rn(ys[n], py);
      float dz = __fsub_rn(zs[n], pz);
      float d  = __fadd_rn(__fadd_rn(__fmul_rn(dx,dx), __fmul_rn(dy,dy)), __fmul_rn(dz,dz));
      float dm = fminf(dmin[n], d); dmin[n] = dm;
      if (dm > v || (dm == v && n < idx)){ v = dm; idx = n; }
    }
    #pragma unroll
    for (int o = 32; o > 0; o >>= 1){
      float v2 = __shfl_down(v, o); int i2 = __shfl_down(idx, o);
      if (v2 > v || (v2 == v && i2 < idx)){ v = v2; idx = i2; }
    }
    if ((t & 63) == 0){ rv[t>>6] = v; ri[t>>6] = idx; }
    __syncthreads();
    if (t == 0){
      float bv = rv[0]; int bi = ri[0];
      for (int w = 1; w < 4; ++w){
        if (rv[w] > bv || (rv[w] == bv && ri[w] < bi)){ bv = rv[w]; bi = ri[w]; }
      }
      bi = min(max(bi, 0), Np-1);
      s_last = bi;
      center[(size_t)(b*Gn+it)*3+0] = xs[bi];
      center[(size_t)(b*Gn+it)*3+1] = ys[bi];
      center[(size_t)(b*Gn+it)*3+2] = zs[bi];
    }
    __syncthreads();
    last = s_last;
  }
}

// ---------------------------------------------------------------- KNN
__global__ __launch_bounds__(256) void knn_kernel(const void* __restrict__ pts,
                                                  const float* __restrict__ center,
                                                  float* __restrict__ nb,
                                                  const int* __restrict__ dflag){
  const int f32 = *dflag;
  int gid = blockIdx.x; int b = gid >> 7;
  __shared__ float d2[1024];
  __shared__ float rv[4]; __shared__ int ri[4];
  int t = threadIdx.x;
  float cx = center[(size_t)gid*3+0], cy = center[(size_t)gid*3+1], cz = center[(size_t)gid*3+2];
  size_t base = (size_t)b * Np * 3;
  for (int n = t; n < Np; n += 256){
    float dx = __fsub_rn(cx, ld(pts, base + n*3+0, f32));
    float dy = __fsub_rn(cy, ld(pts, base + n*3+1, f32));
    float dz = __fsub_rn(cz, ld(pts, base + n*3+2, f32));
    d2[n] = __fadd_rn(__fadd_rn(__fmul_rn(dx,dx), __fmul_rn(dy,dy)), __fmul_rn(dz,dz));
  }
  __syncthreads();
  for (int kk = 0; kk < Kn; ++kk){
    float v = 3e38f; int idx = 0;
    for (int n = t; n < Np; n += 256){
      float d = d2[n];
      if (d < v || (d == v && n < idx)){ v = d; idx = n; }
    }
    #pragma unroll
    for (int o = 32; o > 0; o >>= 1){
      float v2 = __shfl_down(v, o); int i2 = __shfl_down(idx, o);
      if (v2 < v || (v2 == v && i2 < idx)){ v = v2; idx = i2; }
    }
    if ((t & 63) == 0){ rv[t>>6] = v; ri[t>>6] = idx; }
    __syncthreads();
    if (t == 0){
      float bv = rv[0]; int bi = ri[0];
      for (int w = 1; w < 4; ++w){
        if (rv[w] < bv || (rv[w] == bv && ri[w] < bi)){ bv = rv[w]; bi = ri[w]; }
      }
      bi = min(max(bi, 0), Np-1);
      nb[((size_t)gid*Kn+kk)*3+0] = __fsub_rn(ld(pts, base + bi*3+0, f32), cx);
      nb[((size_t)gid*Kn+kk)*3+1] = __fsub_rn(ld(pts, base + bi*3+1, f32), cy);
      nb[((size_t)gid*Kn+kk)*3+2] = __fsub_rn(ld(pts, base + bi*3+2, f32), cz);
      d2[bi] = 3e38f;
    }
    __syncthreads();
  }
}

// ---------------------------------------------------------------- GEMM
template<typename AT, int ACT>
__global__ __launch_bounds__(256) void gemm_bt(const AT* __restrict__ A, int lda,
                                               const void* __restrict__ W, size_t wOff,
                                               const void* __restrict__ bias, size_t bOff,
                                               const void* __restrict__ g,
                                               const void* __restrict__ bb,
                                               float* __restrict__ C, int ldc,
                                               int M, int N, int K,
                                               const int* __restrict__ dflag){
  const int f32 = *dflag;
  __shared__ __align__(16) float As[16][68];
  __shared__ __align__(16) float Ws[16][68];
  int bm = blockIdx.x * 64, bn = blockIdx.y * 64;
  int t = threadIdx.x;
  int tx = t & 15, ty = t >> 4;
  int lm = t >> 2;
  int lk = (t & 3) * 4;
  float acc[4][4] = {};
  for (int k0 = 0; k0 < K; k0 += 16){
    {
      int m = bm + lm;
      #pragma unroll
      for (int i = 0; i < 4; ++i){
        int k = k0 + lk + i;
        As[lk+i][lm] = (k < K) ? toF(A[(size_t)m*lda + k]) : 0.f;
      }
    }
    {
      int n = bn + lm;
      #pragma unroll
      for (int i = 0; i < 4; ++i){
        int k = k0 + lk + i;
        float wv = 0.f;
        if (n < N && k < K) wv = ld(W, wOff + (size_t)n*K + k, f32);
        Ws[lk+i][lm] = wv;
      }
    }
    __syncthreads();
    #pragma unroll
    for (int kk = 0; kk < 16; ++kk){
      float4 av = *(const float4*)(&As[kk][ty*4]);
      float4 wv = *(const float4*)(&Ws[kk][tx*4]);
      float a4[4] = {av.x, av.y, av.z, av.w};
      float w4[4] = {wv.x, wv.y, wv.z, wv.w};
      #pragma unroll
      for (int i = 0; i < 4; ++i)
        #pragma unroll
        for (int j = 0; j < 4; ++j)
          acc[i][j] += a4[i] * w4[j];
    }
    __syncthreads();
  }
  #pragma unroll
  for (int i = 0; i < 4; ++i){
    int m = bm + ty*4 + i;
    #pragma unroll
    for (int j = 0; j < 4; ++j){
      int n = bn + tx*4 + j;
      if (n < N){
        float v = acc[i][j];
        if (bias) v += ld(bias, bOff + n, f32);
        if (ACT == 1){ v = v * (ld(g, n, f32) * BNS) + ld(bb, n, f32); v = fmaxf(v, 0.f); }
        C[(size_t)m*ldc + n] = v;
      }
    }
  }
}

// -------------------------------------------------- encoder max-pools
__global__ __launch_bounds__(256) void maxk_fg(float* __restrict__ f3in){
  int gg = blockIdx.x; int c = threadIdx.x;
  float m = -3e38f;
  for (int k = 0; k < Kn; ++k) m = fmaxf(m, f3in[((size_t)gg*Kn + k)*512 + 256 + c]);
  for (int k = 0; k < Kn; ++k) f3in[((size_t)gg*Kn + k)*512 + c] = m;
}

__global__ __launch_bounds__(384) void maxk_tok(const float* __restrict__ f4, float* __restrict__ tok){
  int gg = blockIdx.x; int c = threadIdx.x;
  float m = -3e38f;
  for (int k = 0; k < Kn; ++k) m = fmaxf(m, f4[((size_t)gg*Kn + k)*DM + c]);
  tok[(size_t)gg*DM + c] = m;
}

// -------------------------------------------------- pos embedding (adds into tok)
__global__ __launch_bounds__(128) void pos_kernel(const float* __restrict__ center,
                                                  const void* __restrict__ w1, const void* __restrict__ b1,
                                                  const void* __restrict__ w2, const void* __restrict__ b2,
                                                  float* __restrict__ tok,
                                                  const int* __restrict__ dflag){
  const int f32 = *dflag;
  int gid = blockIdx.x;
  __shared__ float h1[128]; __shared__ float c3[3];
  int t = threadIdx.x;
  if (t < 3) c3[t] = center[(size_t)gid*3 + t];
  __syncthreads();
  float a = ld(w1,t*3+0,f32)*c3[0] + ld(w1,t*3+1,f32)*c3[1] + ld(w1,t*3+2,f32)*c3[2] + ld(b1,t,f32);
  h1[t] = 0.5f * a * (1.f + erff(a * 0.70710678118654752440f));
  __syncthreads();
  for (int c = t; c < DM; c += 128){
    float s = ld(b2, c, f32);
    for (int j = 0; j < 128; ++j) s += ld(w2, (size_t)c*128 + j, f32) * h1[j];
    tok[(size_t)gid*DM + c] += s;
  }
}

// -------------------------------------------------- stable argsort (rank count)
__global__ __launch_bounds__(128) void sort_kernel(const float* __restrict__ center,
                                                   int* __restrict__ order){
  int bax = blockIdx.x; int b = bax / 3, ax = bax % 3;
  __shared__ float key[128];
  int t = threadIdx.x;
  key[t] = center[(size_t)(b*Gn + t)*3 + ax];
  __syncthreads();
  float kt = key[t]; int r = 0;
  for (int j = 0; j < Gn; ++j){
    float kj = key[j];
    r += (kj < kt || (kj == kt && j < t)) ? 1 : 0;
  }
  r = min(max(r, 0), Gn-1);
  order[b*Ln + ax*Gn + r] = t;
}

// -------------------------------------------------- token gather + res init
__global__ __launch_bounds__(256) void build_h(const float* __restrict__ tok,
                        const int* __restrict__ order,
                        float* __restrict__ h, float* __restrict__ res){
  int i = blockIdx.x * blockDim.x + threadIdx.x;
  if (i >= Bn*Ln*DM) return;
  int c = i % DM; int l = (i / DM) % Ln; int b = i / (DM*Ln);
  int src = order[b*Ln + l];
  src = min(max(src, 0), Gn-1);
  h[i] = tok[((size_t)(b*Gn + src))*DM + c];
  res[i] = 0.f;
}

// -------------------------------------------------- res += h; x = LN(res)*w+b (bf16 out)
__global__ __launch_bounds__(256) void ln_res_kernel(const float* __restrict__ h,
                                                     float* __restrict__ res,
                                                     bf16* __restrict__ x,
                                                     const void* __restrict__ w, size_t wOff,
                                                     const void* __restrict__ bias,
                                                     const int* __restrict__ dflag){
  const int f32 = *dflag;
  int wv = threadIdx.x >> 6, ln = threadIdx.x & 63;
  int tokid = blockIdx.x*4 + wv;
  const float* hr = h + (size_t)tokid*DM;
  float* rr = res + (size_t)tokid*DM;
  bf16* xr = x + (size_t)tokid*DM;
  float v[6]; float s = 0.f;
  #pragma unroll
  for (int i = 0; i < 6; ++i){ int c = ln + 64*i; float t = hr[c] + rr[c]; rr[c] = t; v[i] = t; s += t; }
  #pragma unroll
  for (int o = 32; o > 0; o >>= 1) s += __shfl_xor(s, o);
  float mu = s * (1.f/DM);
  float q = 0.f;
  #pragma unroll
  for (int i = 0; i < 6; ++i){ float d = v[i] - mu; q += d*d; }
  #pragma unroll
  for (int o = 32; o > 0; o >>= 1) q += __shfl_xor(q, o);
  float rstd = rsqrtf(q * (1.f/DM) + EPSf);
  #pragma unroll
  for (int i = 0; i < 6; ++i){ int c = ln + 64*i;
    xr[c] = __float2bfloat16((v[i]-mu)*rstd*ld(w, wOff+c, f32) + ld(bias, wOff+c, f32)); }
}

// -------------------------------------------------- causal depthwise conv + silu
// in-place on xz u-half, register-chunked (16 steps) to amortize alias stalls
__global__ __launch_bounds__(256) void conv_kernel(float* __restrict__ xz,
                                                   const void* __restrict__ cw, size_t cwOff,
                                                   const void* __restrict__ cb, size_t cbOff,
                                                   const int* __restrict__ dflag){
  const int f32 = *dflag;
  int id = blockIdx.x * 256 + threadIdx.x;
  int b = id / DI, d = id % DI;
  float w0 = ld(cw, cwOff + d*4+0, f32), w1 = ld(cw, cwOff + d*4+1, f32);
  float w2 = ld(cw, cwOff + d*4+2, f32), w3 = ld(cw, cwOff + d*4+3, f32);
  float bias = ld(cb, cbOff + d, f32);
  float* p = xz + (size_t)b*Ln*1536 + d;
  float u0 = 0.f, u1 = 0.f, u2 = 0.f;
  for (int c0 = 0; c0 < Ln; c0 += 16){
    float r[16];
    #pragma unroll
    for (int i = 0; i < 16; ++i) r[i] = p[(size_t)(c0+i)*1536];
    float o[16];
    #pragma unroll
    for (int i = 0; i < 16; ++i){
      float v = u0*w0 + u1*w1 + u2*w2 + r[i]*w3 + bias;
      o[i] = v / (1.f + expf(-v));
      u0 = u1; u1 = u2; u2 = r[i];
    }
    #pragma unroll
    for (int i = 0; i < 16; ++i) p[(size_t)(c0+i)*1536] = o[i];
  }
}

// -------------------------------------------------- chunked selective scan
// Phase A: per (b,dch,chunk) block, local scan from h=0 -> S[16], sum dt
__global__ __launch_bounds__(256) void scanA_kernel(const float* __restrict__ xz,
                                                    const float* __restrict__ xdb,
                                                    const void* __restrict__ dpw, size_t dpwOff,
                                                    const void* __restrict__ dpb, size_t dpbOff,
                                                    const void* __restrict__ A_log, size_t AlOff,
                                                    float* __restrict__ SB_S,
                                                    float* __restrict__ SB_dt,
                                                    const int* __restrict__ dflag){
  const int f32 = *dflag;
  __shared__ float sRow[CHS*56];
  int blk = blockIdx.x;                 // (b*3+dch)*NCH + c
  int c = blk % NCH; int bd = blk / NCH; int dch = bd % 3; int b = bd / 3;
  int t = threadIdx.x; int d = dch*256 + t;
  int l0 = c*CHS;
  for (int i = t; i < CHS*56; i += 256) sRow[i] = xdb[((size_t)(b*Ln + l0))*56 + i];
  const float* xzu = xz + ((size_t)b*Ln)*1536 + d;
  float u[CHS];
  #pragma unroll
  for (int i = 0; i < CHS; ++i) u[i] = xzu[(size_t)(l0+i)*1536];
  float w[DTR];
  #pragma unroll
  for (int j = 0; j < DTR; ++j) w[j] = ld(dpw, dpwOff + (size_t)d*DTR + j, f32);
  float a2[DSt], h[DSt];
  #pragma unroll
  for (int s = 0; s < DSt; ++s){ a2[s] = -expf(ld(A_log, AlOff + (size_t)d*DSt + s, f32)) * LOG2E; h[s] = 0.f; }
  float dbias = ld(dpb, dpbOff + d, f32);
  float sumdt = 0.f;
  __syncthreads();
  #pragma unroll
  for (int i = 0; i < CHS; ++i){
    const float* row = &sRow[i*56];
    float dtr = dbias;
    #pragma unroll
    for (int j = 0; j < DTR; ++j) dtr += w[j] * row[j];
    float dtv = fmaxf(dtr, 0.f) + log1pf(expf(-fabsf(dtr)));
    sumdt += dtv;
    float du = dtv * u[i];
    #pragma unroll
    for (int s = 0; s < DSt; ++s)
      h[s] = exp2f(dtv * a2[s]) * h[s] + du * row[24 + s];
  }
  size_t sb = ((size_t)blk*256 + t)*16;
  #pragma unroll
  for (int s = 0; s < DSt; ++s) SB_S[sb + s] = h[s];
  SB_dt[(size_t)blk*256 + t] = sumdt;
}

// Combine: per channel, sequential prefix over chunks; SB_S[c] := h_in(c)
__global__ __launch_bounds__(256) void scanC_kernel(float* __restrict__ SB_S,
                                                    const float* __restrict__ SB_dt,
                                                    const void* __restrict__ A_log, size_t AlOff,
                                                    const int* __restrict__ dflag){
  const int f32 = *dflag;
  int id = blockIdx.x*256 + threadIdx.x;   // 0..3071
  int t = id & 255; int bd = id >> 8;      // bd = b*3+dch
  int d = (bd % 3)*256 + t;
  float a2[DSt];
  #pragma unroll
  for (int s = 0; s < DSt; ++s) a2[s] = -expf(ld(A_log, AlOff + (size_t)d*DSt + s, f32)) * LOG2E;
  float h[DSt];
  #pragma unroll
  for (int s = 0; s < DSt; ++s) h[s] = 0.f;
  for (int c = 0; c < NCH; ++c){
    size_t base = (((size_t)bd*NCH + c)*256 + t)*16;
    float sd = SB_dt[((size_t)bd*NCH + c)*256 + t];
    #pragma unroll
    for (int s = 0; s < DSt; ++s){
      float S = SB_S[base + s];
      SB_S[base + s] = h[s];
      h[s] = exp2f(sd * a2[s]) * h[s] + S;
    }
  }
}

// Phase B: re-run each chunk from correct h_in, produce gated y in-place
__global__ __launch_bounds__(256) void scanB_kernel(float* __restrict__ xz,
                                                    const float* __restrict__ xdb,
                                                    const void* __restrict__ dpw, size_t dpwOff,
                                                    const void* __restrict__ dpb, size_t dpbOff,
                                                    const void* __restrict__ A_log, size_t AlOff,
                                                    const void* __restrict__ Dp, size_t DpOff,
                                                    const float* __restrict__ SB_S,
                                                    const int* __restrict__ dflag){
  const int f32 = *dflag;
  __shared__ float sRow[CHS*56];
  int blk = blockIdx.x;
  int c = blk % NCH; int bd = blk / NCH; int dch = bd % 3; int b = bd / 3;
  int t = threadIdx.x; int d = dch*256 + t;
  int l0 = c*CHS;
  for (int i = t; i < CHS*56; i += 256) sRow[i] = xdb[((size_t)(b*Ln + l0))*56 + i];
  float* xzu = xz + ((size_t)b*Ln)*1536 + d;
  float u[CHS], z[CHS];
  #pragma unroll
  for (int i = 0; i < CHS; ++i){
    u[i] = xzu[(size_t)(l0+i)*1536];
    z[i] = xzu[(size_t)(l0+i)*1536 + DI];
  }
  float w[DTR];
  #pragma unroll
  for (int j = 0; j < DTR; ++j) w[j] = ld(dpw, dpwOff + (size_t)d*DTR + j, f32);
  float a2[DSt], h[DSt];
  #pragma unroll
  for (int s = 0; s < DSt; ++s) a2[s] = -expf(ld(A_log, AlOff + (size_t)d*DSt + s, f32)) * LOG2E;
  size_t sb = ((size_t)blk*256 + t)*16;
  #pragma unroll
  for (int s = 0; s < DSt; ++s) h[s] = SB_S[sb + s];
  float dbias = ld(dpb, dpbOff + d, f32);
  float Dd = ld(Dp, DpOff + d, f32);
  __syncthreads();
  #pragma unroll
  for (int i = 0; i < CHS; ++i){
    const float* row = &sRow[i*56];
    float dtr = dbias;
    #pragma unroll
    for (int j = 0; j < DTR; ++j) dtr += w[j] * row[j];
    float dtv = fmaxf(dtr, 0.f) + log1pf(expf(-fabsf(dtr)));
    float du = dtv * u[i];
    float yv = 0.f;
    #pragma unroll
    for (int s = 0; s < DSt; ++s){
      h[s] = exp2f(dtv * a2[s]) * h[s] + du * row[24 + s];
      yv += h[s] * row[40 + s];
    }
    float sig = 1.f / (1.f + expf(-z[i]));
    xzu[(size_t)(l0+i)*1536] = (yv + u[i]*Dd) * (z[i] * sig);
  }
}

// -------------------------------------------------- final two LayerNorms
__global__ __launch_bounds__(256) void final_ln_kernel(const float* __restrict__ h,
                                                       const float* __restrict__ res,
                                                       const void* w1, const void* b1,
                                                       const void* w2, const void* b2,
                                                       float* __restrict__ x,
                                                       const int* __restrict__ dflag){
  const int f32 = *dflag;
  int wv = threadIdx.x >> 6, ln = threadIdx.x & 63;
  int tokid = blockIdx.x*4 + wv;
  const float* hr = h + (size_t)tokid*DM;
  const float* rr = res + (size_t)tokid*DM;
  float* xr = x + (size_t)tokid*DM;
  float v[6]; float s = 0.f;
  #pragma unroll
  for (int i = 0; i < 6; ++i){ int c = ln + 64*i; v[i] = hr[c] + rr[c]; s += v[i]; }
  #pragma unroll
  for (int o = 32; o > 0; o >>= 1) s += __shfl_xor(s, o);
  float mu = s * (1.f/DM); float q = 0.f;
  #pragma unroll
  for (int i = 0; i < 6; ++i){ float dd = v[i]-mu; q += dd*dd; }
  #pragma unroll
  for (int o = 32; o > 0; o >>= 1) q += __shfl_xor(q, o);
  float rstd = rsqrtf(q * (1.f/DM) + EPSf);
  float u[6]; float s2 = 0.f;
  #pragma unroll
  for (int i = 0; i < 6; ++i){ int c = ln + 64*i; u[i] = (v[i]-mu)*rstd*ld(w1,c,f32) + ld(b1,c,f32); s2 += u[i]; }
  #pragma unroll
  for (int o = 32; o > 0; o >>= 1) s2 += __shfl_xor(s2, o);
  float mu2 = s2 * (1.f/DM); float q2 = 0.f;
  #pragma unroll
  for (int i = 0; i < 6; ++i){ float dd = u[i]-mu2; q2 += dd*dd; }
  #pragma unroll
  for (int o = 32; o > 0; o >>= 1) q2 += __shfl_xor(q2, o);
  float rstd2 = rsqrtf(q2 * (1.f/DM) + EPSf);
  #pragma unroll
  for (int i = 0; i < 6; ++i){ int c = ln + 64*i; xr[c] = (u[i]-mu2)*rstd2*ld(w2,c,f32) + ld(b2,c,f32); }
}

// -------------------------------------------------- mean over L + MLP head
__global__ __launch_bounds__(384) void head_kernel(const float* __restrict__ x,
    const void* w1, const void* b1, const void* g1, const void* bb1,
    const void* w2, const void* b2, const void* g2, const void* bb2,
    const void* w3, const void* b3, void* __restrict__ out,
    const int* __restrict__ dflag){
  const int f32 = *dflag;
  int b = blockIdx.x; int t = threadIdx.x;
  __shared__ float feat[DM]; __shared__ float h1[256]; __shared__ float h2[256];
  float s = 0.f;
  for (int l = 0; l < Ln; ++l) s += x[((size_t)(b*Ln + l))*DM + t];
  feat[t] = s * (1.f/Ln);
  __syncthreads();
  if (t < 256){
    float a = ld(b1, t, f32);
    for (int j = 0; j < DM; ++j) a += ld(w1, (size_t)t*DM + j, f32) * feat[j];
    a = a * (ld(g1,t,f32) * BNS) + ld(bb1,t,f32);
    h1[t] = fmaxf(a, 0.f);
  }
  __syncthreads();
  if (t < 256){
    float a = ld(b2, t, f32);
    for (int j = 0; j < 256; ++j) a += ld(w2, (size_t)t*256 + j, f32) * h1[j];
    a = a * (ld(g2,t,f32) * BNS) + ld(bb2,t,f32);
    h2[t] = fmaxf(a, 0.f);
  }
  __syncthreads();
  if (t < CLSn){
    float a = ld(b3, t, f32);
    for (int j = 0; j < 256; ++j) a += ld(w3, (size_t)t*256 + j, f32) * h2[j];
    if (f32) ((float*)out)[b*CLSn + t] = a;
    else     ((bf16*)out)[b*CLSn + t] = __float2bfloat16(a);
  }
}

extern "C" void kernel_launch(void* const* d_in, const int* in_sizes, int n_in,
                              void* d_out, int out_size, void* d_ws, size_t ws_size,
                              hipStream_t stream) {
  if (n_in < 42) return;
  if (out_size < Bn*CLSn) return;
  constexpr size_t WS_FLOATS = 3919936; // hb + res + U + flag
  if (ws_size < WS_FLOATS * sizeof(float)) return;

  const void* pts       = d_in[0];
  const void* enc_w1    = d_in[1];  const void* enc_b1    = d_in[2];
  const void* enc_bn1_g = d_in[3];  const void* enc_bn1_b = d_in[4];
  const void* enc_w2    = d_in[5];  const void* enc_b2    = d_in[6];
  const void* enc_w3    = d_in[7];  const void* enc_b3    = d_in[8];
  const void* enc_bn2_g = d_in[9];  const void* enc_bn2_b = d_in[10];
  const void* enc_w4    = d_in[11]; const void* enc_b4    = d_in[12];
  const void* pos_w1    = d_in[13]; const void* pos_b1    = d_in[14];
  const void* pos_w2    = d_in[15]; const void* pos_b2    = d_in[16];
  const void* ln_w      = d_in[17]; const void* ln_b      = d_in[18];
  const void* in_proj_w = d_in[19];
  const void* conv_w    = d_in[20]; const void* conv_b    = d_in[21];
  const void* x_proj_w  = d_in[22];
  const void* dt_proj_w = d_in[23]; const void* dt_proj_b = d_in[24];
  const void* A_log     = d_in[25]; const void* D_param   = d_in[26];
  const void* out_proj_w= d_in[27];
  const void* normf_w   = d_in[28]; const void* normf_b   = d_in[29];
  const void* norm_w    = d_in[30]; const void* norm_b    = d_in[31];
  const void* head_w1   = d_in[32]; const void* head_b1   = d_in[33];
  const void* head_bn1_g= d_in[34]; const void* head_bn1_b= d_in[35];
  const void* head_w2   = d_in[36]; const void* head_b2   = d_in[37];
  const void* head_bn2_g= d_in[38]; const void* head_bn2_b= d_in[39];
  const void* head_w3   = d_in[40]; const void* head_b3   = d_in[41];

  float* ws = (float*)d_ws;
  float* hb   = ws;                   // 589,824 floats
  float* resb = ws + 589824;          // 589,824
  float* U    = ws + 1179648;         // 2,740,224
  int* dflag  = (int*)(ws + 3919872);
  // setup/encoder view of U
  float* center = U;
  float* nb     = U + 1536;
  float* tok    = U + 50688;
  int*   order  = (int*)(U + 247296);
  float* eb0    = U + 262144;
  float* eb1    = U + 1310720;
  // mamba view of U
  float* xz   = U;                      // 2,359,296
  float* xdb  = U + 2359296;            // 86,016
  bf16*  xb   = (bf16*)(U + 2445312);   // 589,824 bf16 (consumed by in_proj)
  float* SBdt = U + 2445312 + 36864;    // 36,864 floats (after-xb area reuse is unsafe;
                                        // place in the second half of the xb float region)
  float* SBS  = hb;                     // 589,824 floats, dead between ln_res and out_proj
  float* xf   = U;

  detect_kernel<<<1, 64, 0, stream>>>(pts, dflag);

  fps_kernel<<<Bn, 256, 0, stream>>>(pts, center, dflag);
  knn_kernel<<<Bn*Gn, 256, 0, stream>>>(pts, center, nb, dflag);

  for (int ch = 0; ch < 8; ++ch){
    const float* nb_c = nb + (size_t)ch*2048*3;
    float* tok_c = tok + (size_t)ch*64*DM;
    gemm_bt<float,1><<<dim3(32,2), 256, 0, stream>>>(nb_c, 3, enc_w1, 0, enc_b1, 0,
        enc_bn1_g, enc_bn1_b, eb1, 128, 2048, 128, 3, dflag);
    gemm_bt<float,0><<<dim3(32,4), 256, 0, stream>>>(eb1, 128, enc_w2, 0, enc_b2, 0,
        nullptr, nullptr, eb0 + 256, 512, 2048, 256, 128, dflag);
    maxk_fg<<<64, 256, 0, stream>>>(eb0);
    gemm_bt<float,1><<<dim3(32,8), 256, 0, stream>>>(eb0, 512, enc_w3, 0, enc_b3, 0,
        enc_bn2_g, enc_bn2_b, eb1, 512, 2048, 512, 512, dflag);
    gemm_bt<float,0><<<dim3(32,6), 256, 0, stream>>>(eb1, 512, enc_w4, 0, enc_b4, 0,
        nullptr, nullptr, eb0, 384, 2048, 384, 512, dflag);
    maxk_tok<<<64, 384, 0, stream>>>(eb0, tok_c);
  }

  pos_kernel<<<Bn*Gn, 128, 0, stream>>>(center, pos_w1, pos_b1, pos_w2, pos_b2, tok, dflag);
  sort_kernel<<<Bn*3, 128, 0, stream>>>(center, order);
  build_h<<<(Bn*Ln*DM + 255)/256, 256, 0, stream>>>(tok, order, hb, resb);

  for (int l = 0; l < DEPTH; ++l){
    size_t o_ln  = (size_t)l*DM;
    size_t o_ip  = (size_t)l*1536*DM;
    size_t o_cw  = (size_t)l*DI*4;
    size_t o_cb  = (size_t)l*DI;
    size_t o_xp  = (size_t)l*56*DI;
    size_t o_dpw = (size_t)l*DI*DTR;
    size_t o_dpb = (size_t)l*DI;
    size_t o_Al  = (size_t)l*DI*DSt;
    size_t o_Dp  = (size_t)l*DI;
    size_t o_op  = (size_t)l*DM*DI;

    ln_res_kernel<<<Bn*Ln/4, 256, 0, stream>>>(hb, resb, xb, ln_w, o_ln, ln_b, dflag);
    gemm_bt<bf16,0><<<dim3(24,24), 256, 0, stream>>>(xb, DM, in_proj_w, o_ip,
        nullptr, 0, nullptr, nullptr, xz, 1536, Bn*Ln, 1536, DM, dflag);
    conv_kernel<<<Bn*DI/256, 256, 0, stream>>>(xz, conv_w, o_cw, conv_b, o_cb, dflag);
    gemm_bt<float,0><<<dim3(24,1), 256, 0, stream>>>(xz, 1536, x_proj_w, o_xp,
        nullptr, 0, nullptr, nullptr, xdb, 56, Bn*Ln, 56, DI, dflag);
    // chunked parallel selective scan (SBS aliases hb: dead here, rewritten by out_proj)
    scanA_kernel<<<Bn*3*NCH, 256, 0, stream>>>(xz, xdb, dt_proj_w, o_dpw, dt_proj_b, o_dpb,
        A_log, o_Al, SBS, SBdt, dflag);
    scanC_kernel<<<12, 256, 0, stream>>>(SBS, SBdt, A_log, o_Al, dflag);
    scanB_kernel<<<Bn*3*NCH, 256, 0, stream>>>(xz, xdb, dt_proj_w, o_dpw, dt_proj_b, o_dpb,
        A_log, o_Al, D_param, o_Dp, SBS, dflag);
    gemm_bt<float,0><<<dim3(24,6), 256, 0, stream>>>(xz, 1536, out_proj_w, o_op,
        nullptr, 0, nullptr, nullptr, hb, DM, Bn*Ln, DM, DI, dflag);
  }

  final_ln_kernel<<<Bn*Ln/4, 256, 0, stream>>>(hb, resb, normf_w, normf_b, norm_w, norm_b, xf, dflag);
  head_kernel<<<Bn, 384, 0, stream>>>(xf, head_w1, head_b1, head_bn1_g, head_bn1_b,
                                      head_w2, head_b2, head_bn2_g, head_bn2_b,
                                      head_w3, head_b3, d_out, dflag);
}